// Round 9
// baseline (155.227 us; speedup 1.0000x reference)
//
#include <hip/hip_runtime.h>

#define H_ 128
#define W_ 160
#define HW_ (H_ * W_)
#define TILES_ 256        // dst tiles per batch: (row, x-half) = 128 x 2
#define SEG_CAP_ 8192     // events per tile seg: ~2.5x mean (~3300)
#define EVB_ 2048         // events per bin_pass block (256 thr x 8)
#define HASH_ 8192        // LDS hash entries; >= SEG_CAP_ guarantees termination
#define EMPTY_ 0xFFFFFFFFu

__device__ __forceinline__ unsigned mix32(unsigned h) {
    h ^= h >> 16; h *= 0x85ebca6bu;
    h ^= h >> 13; h *= 0xc2b2ae35u;
    h ^= h >> 16;
    return h;
}

// ---------------------------------------------------------------------------
// Pass 0: interleave planar flow -> float2 (one 8B gather per event later),
// and zero the tails table (folded in: saves a memset dispatch).
// ---------------------------------------------------------------------------
__global__ __launch_bounds__(256) void repack_flow(
    const float* __restrict__ flow, float2* __restrict__ flow2,
    unsigned* __restrict__ tails, int ntails, int total)
{
    int i = blockIdx.x * blockDim.x + threadIdx.x;
    if (i < ntails) tails[i] = 0u;
    if (i >= total) return;
    int b = i / HW_, idx = i - b * HW_;
    const float* fl = flow + (size_t)b * 2 * HW_;
    flow2[i] = make_float2(fl[idx], fl[HW_ + idx]);
}

// ---------------------------------------------------------------------------
// Pass A: warp math per event, bin payloads by dst tile. 256-thread blocks,
// 8 blocks/CU, grid 1960x4: finer drain granularity than r8's 980 blocks
// (occupancy counter showed ~50% = tail drain). All 8 event loads issued
// before the 8 gathers -> max MLP.
// Cost model: ~13 us stream + 1 divergent gather unit + 1 divergent scatter
// unit (~15 us each) — both structural for exact dst grouping.
// ---------------------------------------------------------------------------
__global__ __launch_bounds__(256, 8) void bin_pass(
    const float4* __restrict__ ev,       // (B, N, 4): ts, y, x, p
    const float2* __restrict__ flow2,    // (B, HW)
    unsigned* __restrict__ tails,        // (B*TILES_), pre-zeroed
    unsigned* __restrict__ segs,         // (B*TILES_, SEG_CAP_)
    int N)
{
    __shared__ unsigned cnt[TILES_];
    __shared__ unsigned base[TILES_];

    const int b = blockIdx.y;
    const int i0 = blockIdx.x * EVB_;
    const float4* evb = ev + (size_t)b * N;
    const float2* flb = flow2 + (size_t)b * HW_;

    cnt[threadIdx.x] = 0u;
    __syncthreads();

    float4 e[8];
    int idx[8];
#pragma unroll
    for (int k = 0; k < 8; ++k) {                    // 8 stream loads in flight
        idx[k] = i0 + k * 256 + (int)threadIdx.x;
        e[k] = (idx[k] < N) ? evb[idx[k]] : make_float4(0.f, 0.f, 0.f, 0.f);
    }
    float2 f[8];
    int src[8];
#pragma unroll
    for (int k = 0; k < 8; ++k) {                    // 8 gathers in flight
        src[k] = (int)e[k].y * W_ + (int)e[k].z;     // y,x exact small ints
        f[k] = flb[src[k]];
    }

    unsigned pay[8], rank[8];
    unsigned short tt[8];
    bool val[8];
#pragma unroll
    for (int k = 0; k < 8; ++k) {
        val[k] = false;
        if (idx[k] < N) {
            // Bit-exact numpy order: y + ((1 - ts) * f) * 160, no FMA.
            float dt = __fsub_rn(1.0f, e[k].x);
            float wy = __fadd_rn(e[k].y, __fmul_rn(__fmul_rn(dt, f[k].y), 160.0f));
            float wx = __fadd_rn(e[k].z, __fmul_rn(__fmul_rn(dt, f[k].x), 160.0f));
            float ry = rintf(wy);                    // round half to even
            float rx = rintf(wx);
            // Validity on rounded floats (-0.0 valid, like the ref).
            if (ry >= 0.0f && ry < (float)H_ && rx >= 0.0f && rx < (float)W_) {
                int iy = (int)ry, ix = (int)rx;
                unsigned c = (e[k].w > 0.0f) ? 0u : 1u;
                unsigned t = (unsigned)(iy * 2 + (ix >= 80));
                pay[k] = (unsigned)src[k] | (c << 15) | ((unsigned)ix << 16);
                tt[k] = (unsigned short)t;
                val[k] = true;
                rank[k] = atomicAdd(&cnt[t], 1u);    // LDS rank within block
            }
        }
    }
    __syncthreads();

    {
        unsigned c = cnt[threadIdx.x];
        base[threadIdx.x] =
            c ? atomicAdd(&tails[b * TILES_ + threadIdx.x], c) : 0u;
    }
    __syncthreads();

#pragma unroll
    for (int k = 0; k < 8; ++k) {
        if (val[k]) {
            unsigned pos = base[tt[k]] + rank[k];
            if (pos < SEG_CAP_)                      // ~never taken
                segs[((size_t)(b * TILES_ + tt[k])) * SEG_CAP_ + pos] = pay[k];
        }
    }
}

// ---------------------------------------------------------------------------
// Pass B: one block per (b, dst tile). Exact dedup hash set on the payload
// key + count/contrib accumulators, all in LDS; fused divide + plain store.
// Termination: <= SEG_CAP_ = HASH_ events => empty slot always reachable.
// ---------------------------------------------------------------------------
__global__ __launch_bounds__(512) void accum_pass(
    const unsigned* __restrict__ tails,
    const unsigned* __restrict__ segs,
    float* __restrict__ out)                          // (B, 2, H, W)
{
    __shared__ unsigned hset[HASH_];                  // 32 KB
    __shared__ unsigned cntl[2 * 80];
    __shared__ unsigned cbl[2 * 80];

    const int bt = blockIdx.x;                        // b*TILES_ + t
    const int b = bt >> 8, t = bt & 255;
    const int row = t >> 1, half = t & 1;

    for (int j = threadIdx.x; j < HASH_; j += 512) hset[j] = EMPTY_;
    if (threadIdx.x < 160) { cntl[threadIdx.x] = 0u; cbl[threadIdx.x] = 0u; }
    __syncthreads();

    const unsigned n = min(tails[bt], (unsigned)SEG_CAP_);
    const unsigned* seg = segs + (size_t)bt * SEG_CAP_;
    volatile unsigned* hv = hset;

    for (unsigned i = threadIdx.x; i < n; i += 512) {
        unsigned key = seg[i];                        // src | pol<<15 | x<<16
        unsigned c = (key >> 15) & 1u;
        unsigned x = (key >> 16) & 0xFFu;
        unsigned cl = c * 80 + (x - (unsigned)half * 80u);

        unsigned h = mix32(key) & (HASH_ - 1);
        for (;;) {
            unsigned cur = hv[h];                     // cheap pre-read
            if (cur == key) break;                    // duplicate triple
            if (cur == EMPTY_) {
                unsigned prev = atomicCAS(&hset[h], EMPTY_, key);
                if (prev == EMPTY_) {                 // first (pol,src,fw)
                    atomicAdd(&cbl[cl], 1u);
                    break;
                }
                if (prev == key) break;               // raced duplicate
            }
            h = (h + 1) & (HASH_ - 1);
        }
        atomicAdd(&cntl[cl], 1u);                     // event count
    }
    __syncthreads();

    if (threadIdx.x < 160) {
        unsigned c = threadIdx.x / 80;
        unsigned xl = threadIdx.x % 80;
        unsigned cnt = cntl[threadIdx.x], cb = cbl[threadIdx.x];
        float r = (float)cnt;                         // cnt < 2^24: exact
        if (cb > 0u) r = __fdiv_rn(r, (float)cb);
        out[((size_t)(b * 2 + c)) * HW_ + row * W_ + half * 80 + xl] = r;
    }
}

extern "C" void kernel_launch(void* const* d_in, const int* in_sizes, int n_in,
                              void* d_out, int out_size, void* d_ws, size_t ws_size,
                              hipStream_t stream) {
    const float*  flow = (const float*)d_in[0];
    const float4* ev   = (const float4*)d_in[1];
    // d_in[2] (pol_mask) is redundant with event_list's p column — not read.

    int B = in_sizes[0] / (2 * HW_);          // = 4
    int N = in_sizes[1] / (B * 4);            // = 1,000,000

    // Workspace: [tails u32 x B*TILES_][segs u32 x B*TILES_*SEG_CAP_][flow2]
    unsigned* tails = (unsigned*)d_ws;
    unsigned* segs  = tails + (size_t)B * TILES_;
    float2*   flow2 = (float2*)(segs + (size_t)B * TILES_ * SEG_CAP_);

    int total = B * HW_;
    repack_flow<<<(total + 255) / 256, 256, 0, stream>>>(flow, flow2, tails,
                                                         B * TILES_, total);

    dim3 gridA((N + EVB_ - 1) / EVB_, B);
    bin_pass<<<gridA, 256, 0, stream>>>(ev, flow2, tails, segs, N);

    accum_pass<<<B * TILES_, 512, 0, stream>>>(tails, segs, (float*)d_out);
}

// Round 10
// 147.116 us; speedup vs baseline: 1.0551x; 1.0551x over previous
//
#include <hip/hip_runtime.h>

#define H_ 128
#define W_ 160
#define HW_ (H_ * W_)
#define TILES_ 256        // dst tiles per batch: (row, x-half) = 128 x 2
#define SEG_CAP_ 8192     // events per tile seg: ~2.5x mean (~3300)
#define EVB_ 4096         // events per bin_pass block (512 thr x 8)
                          // EVB >= 4096 keeps per-(block,tile) runs >= ~64B:
                          // r9 (EVB 2048) doubled WRITE_SIZE 13->26 MB.
#define HASH_ 8192        // LDS hash entries; >= SEG_CAP_ guarantees termination
#define EMPTY_ 0xFFFFFFFFu

__device__ __forceinline__ unsigned mix32(unsigned h) {
    h ^= h >> 16; h *= 0x85ebca6bu;
    h ^= h >> 13; h *= 0xc2b2ae35u;
    h ^= h >> 16;
    return h;
}

// ---------------------------------------------------------------------------
// Pass 0: interleave planar flow -> float2 (one 8B gather per event later),
// and zero the tails table (folded in: saves a memset dispatch).
// ---------------------------------------------------------------------------
__global__ __launch_bounds__(256) void repack_flow(
    const float* __restrict__ flow, float2* __restrict__ flow2,
    unsigned* __restrict__ tails, int ntails, int total)
{
    int i = blockIdx.x * blockDim.x + threadIdx.x;
    if (i < ntails) tails[i] = 0u;
    if (i >= total) return;
    int b = i / HW_, idx = i - b * HW_;
    const float* fl = flow + (size_t)b * 2 * HW_;
    flow2[i] = make_float2(fl[idx], fl[HW_ + idx]);
}

// ---------------------------------------------------------------------------
// Pass A (r8 optimum): warp math per event, bin payloads by dst tile.
// 512-thread blocks, EVB 4096. Cost model (validated r5-r9): ~13 us stream +
// ~15 us divergent gather unit + ~15 us divergent scatter unit; both units
// structural for exact dst grouping (flow is random per pixel).
// ---------------------------------------------------------------------------
__global__ __launch_bounds__(512, 8) void bin_pass(
    const float4* __restrict__ ev,       // (B, N, 4): ts, y, x, p
    const float2* __restrict__ flow2,    // (B, HW)
    unsigned* __restrict__ tails,        // (B*TILES_), pre-zeroed
    unsigned* __restrict__ segs,         // (B*TILES_, SEG_CAP_)
    int N)
{
    __shared__ unsigned cnt[TILES_];
    __shared__ unsigned base[TILES_];

    const int b = blockIdx.y;
    const int i0 = blockIdx.x * EVB_;
    const float4* evb = ev + (size_t)b * N;
    const float2* flb = flow2 + (size_t)b * HW_;

    for (int j = threadIdx.x; j < TILES_; j += 512) cnt[j] = 0u;
    __syncthreads();

    unsigned pay[8], rank[8];
    unsigned short tt[8];
    bool val[8];

#pragma unroll
    for (int half = 0; half < 2; ++half) {
        float4 e[4];
        int idx[4];
#pragma unroll
        for (int k = 0; k < 4; ++k) {               // batch the stream loads
            idx[k] = i0 + (half * 4 + k) * 512 + (int)threadIdx.x;
            e[k] = (idx[k] < N) ? evb[idx[k]]
                                : make_float4(0.f, 0.f, 0.f, 0.f);
        }
        float2 f[4];
        int src[4];
#pragma unroll
        for (int k = 0; k < 4; ++k) {               // batch the gathers
            src[k] = (int)e[k].y * W_ + (int)e[k].z;
            f[k] = flb[src[k]];
        }
#pragma unroll
        for (int k = 0; k < 4; ++k) {
            int kk = half * 4 + k;
            val[kk] = false;
            if (idx[k] < N) {
                // Bit-exact numpy order: y + ((1 - ts) * f) * 160, no FMA.
                float dt = __fsub_rn(1.0f, e[k].x);
                float wy = __fadd_rn(e[k].y,
                                     __fmul_rn(__fmul_rn(dt, f[k].y), 160.0f));
                float wx = __fadd_rn(e[k].z,
                                     __fmul_rn(__fmul_rn(dt, f[k].x), 160.0f));
                float ry = rintf(wy);               // round half to even
                float rx = rintf(wx);
                // Validity on rounded floats (-0.0 valid, like the ref).
                if (ry >= 0.0f && ry < (float)H_ &&
                    rx >= 0.0f && rx < (float)W_) {
                    int iy = (int)ry, ix = (int)rx;
                    unsigned c = (e[k].w > 0.0f) ? 0u : 1u;
                    unsigned t = (unsigned)(iy * 2 + (ix >= 80));
                    pay[kk] = (unsigned)src[k] | (c << 15)
                            | ((unsigned)ix << 16);
                    tt[kk] = (unsigned short)t;
                    val[kk] = true;
                    rank[kk] = atomicAdd(&cnt[t], 1u);   // LDS rank
                }
            }
        }
    }
    __syncthreads();

    if (threadIdx.x < TILES_) {
        unsigned c = cnt[threadIdx.x];
        base[threadIdx.x] = c ? atomicAdd(&tails[b * TILES_ + threadIdx.x], c)
                              : 0u;
    }
    __syncthreads();

#pragma unroll
    for (int kk = 0; kk < 8; ++kk) {
        if (val[kk]) {
            unsigned pos = base[tt[kk]] + rank[kk];
            if (pos < SEG_CAP_)                      // ~never taken
                segs[((size_t)(b * TILES_ + tt[kk])) * SEG_CAP_ + pos]
                    = pay[kk];
        }
    }
}

// ---------------------------------------------------------------------------
// Pass B: one block per (b, dst tile). Exact dedup hash set on the payload
// key + count/contrib accumulators, all in LDS; fused divide + plain store.
// Termination: <= SEG_CAP_ = HASH_ events => empty slot always reachable.
// ---------------------------------------------------------------------------
__global__ __launch_bounds__(512) void accum_pass(
    const unsigned* __restrict__ tails,
    const unsigned* __restrict__ segs,
    float* __restrict__ out)                          // (B, 2, H, W)
{
    __shared__ unsigned hset[HASH_];                  // 32 KB
    __shared__ unsigned cntl[2 * 80];
    __shared__ unsigned cbl[2 * 80];

    const int bt = blockIdx.x;                        // b*TILES_ + t
    const int b = bt >> 8, t = bt & 255;
    const int row = t >> 1, half = t & 1;

    for (int j = threadIdx.x; j < HASH_; j += 512) hset[j] = EMPTY_;
    if (threadIdx.x < 160) { cntl[threadIdx.x] = 0u; cbl[threadIdx.x] = 0u; }
    __syncthreads();

    const unsigned n = min(tails[bt], (unsigned)SEG_CAP_);
    const unsigned* seg = segs + (size_t)bt * SEG_CAP_;
    volatile unsigned* hv = hset;

    for (unsigned i = threadIdx.x; i < n; i += 512) {
        unsigned key = seg[i];                        // src | pol<<15 | x<<16
        unsigned c = (key >> 15) & 1u;
        unsigned x = (key >> 16) & 0xFFu;
        unsigned cl = c * 80 + (x - (unsigned)half * 80u);

        unsigned h = mix32(key) & (HASH_ - 1);
        for (;;) {
            unsigned cur = hv[h];                     // cheap pre-read
            if (cur == key) break;                    // duplicate triple
            if (cur == EMPTY_) {
                unsigned prev = atomicCAS(&hset[h], EMPTY_, key);
                if (prev == EMPTY_) {                 // first (pol,src,fw)
                    atomicAdd(&cbl[cl], 1u);
                    break;
                }
                if (prev == key) break;               // raced duplicate
            }
            h = (h + 1) & (HASH_ - 1);
        }
        atomicAdd(&cntl[cl], 1u);                     // event count
    }
    __syncthreads();

    if (threadIdx.x < 160) {
        unsigned c = threadIdx.x / 80;
        unsigned xl = threadIdx.x % 80;
        unsigned cnt = cntl[threadIdx.x], cb = cbl[threadIdx.x];
        float r = (float)cnt;                         // cnt < 2^24: exact
        if (cb > 0u) r = __fdiv_rn(r, (float)cb);
        out[((size_t)(b * 2 + c)) * HW_ + row * W_ + half * 80 + xl] = r;
    }
}

extern "C" void kernel_launch(void* const* d_in, const int* in_sizes, int n_in,
                              void* d_out, int out_size, void* d_ws, size_t ws_size,
                              hipStream_t stream) {
    const float*  flow = (const float*)d_in[0];
    const float4* ev   = (const float4*)d_in[1];
    // d_in[2] (pol_mask) is redundant with event_list's p column — not read.

    int B = in_sizes[0] / (2 * HW_);          // = 4
    int N = in_sizes[1] / (B * 4);            // = 1,000,000

    // Workspace: [tails u32 x B*TILES_][segs u32 x B*TILES_*SEG_CAP_][flow2]
    unsigned* tails = (unsigned*)d_ws;
    unsigned* segs  = tails + (size_t)B * TILES_;
    float2*   flow2 = (float2*)(segs + (size_t)B * TILES_ * SEG_CAP_);

    int total = B * HW_;
    repack_flow<<<(total + 255) / 256, 256, 0, stream>>>(flow, flow2, tails,
                                                         B * TILES_, total);

    dim3 gridA((N + EVB_ - 1) / EVB_, B);
    bin_pass<<<gridA, 512, 0, stream>>>(ev, flow2, tails, segs, N);

    accum_pass<<<B * TILES_, 512, 0, stream>>>(tails, segs, (float*)d_out);
}

// Round 11
// 141.197 us; speedup vs baseline: 1.0994x; 1.0419x over previous
//
#include <hip/hip_runtime.h>

#define H_ 128
#define W_ 160
#define HW_ (H_ * W_)
#define TILES_ 256        // dst tiles per batch: (row, x-half) = 128 x 2
#define SEG_CAP_ 8192     // events per tile seg: ~2.5x mean (~3300)
#define EVB_ 16384        // events per bin_pass block (1024 thr x 16)
#define LDSPIX_ 20096     // flow pixels cached in LDS (157 KB); the last
                          // 384 pixels (1.9% of events) gather from global.
                          // 20096*8 + 2048 static = 162816 B < 163840 max.
#define HASH_ 8192        // LDS hash entries; >= SEG_CAP_ guarantees termination
#define EMPTY_ 0xFFFFFFFFu

__device__ __forceinline__ unsigned mix32(unsigned h) {
    h ^= h >> 16; h *= 0x85ebca6bu;
    h ^= h >> 13; h *= 0xc2b2ae35u;
    h ^= h >> 16;
    return h;
}

// ---------------------------------------------------------------------------
// Pass A: warp math per event, bin payloads by dst tile. The per-batch flow
// table (160 KB) lives in LDS: the former ~15 us divergent global gather unit
// becomes ~244 ds_read_b64 wave-instructions per CU (~1 us). 248 blocks
// (1 per CU, 16 waves each), EVB 16384 -> per-(block,tile) runs ~64 payloads
// = 256 B: better store coalescing than r8's ~56 B.
// ---------------------------------------------------------------------------
__global__ __launch_bounds__(1024) void bin_pass(
    const float4* __restrict__ ev,       // (B, N, 4): ts, y, x, p
    const float* __restrict__ flow,      // (B, 2, HW) planar: ch0=fx, ch1=fy
    unsigned* __restrict__ tails,        // (B*TILES_), pre-zeroed
    unsigned* __restrict__ segs,         // (B*TILES_, SEG_CAP_)
    int N)
{
    extern __shared__ float2 lflow[];    // LDSPIX_ entries (dynamic, 157 KB)
    __shared__ unsigned cnt[TILES_];
    __shared__ unsigned base[TILES_];

    const int b = blockIdx.y;
    const int i0 = blockIdx.x * EVB_;
    const float4* evb = ev + (size_t)b * N;
    const float* fxp = flow + (size_t)b * 2 * HW_;   // fx plane
    const float* fyp = fxp + HW_;                    // fy plane

    // Fill LDS flow cache (coalesced planar reads) + zero tile counters.
    for (int j = threadIdx.x; j < LDSPIX_; j += 1024)
        lflow[j] = make_float2(fxp[j], fyp[j]);
    if (threadIdx.x < TILES_) cnt[threadIdx.x] = 0u;
    __syncthreads();

    unsigned pay[16], rank[16];
    unsigned short tt[16];
    bool val[16];

#pragma unroll
    for (int q = 0; q < 4; ++q) {                    // 4 sub-batches of 4
        float4 e[4];
        int idx[4];
#pragma unroll
        for (int k = 0; k < 4; ++k) {                // stream loads in flight
            idx[k] = i0 + (q * 4 + k) * 1024 + (int)threadIdx.x;
            e[k] = (idx[k] < N) ? evb[idx[k]]
                                : make_float4(0.f, 0.f, 0.f, 0.f);
        }
        float2 f[4];
        int src[4];
#pragma unroll
        for (int k = 0; k < 4; ++k) {                // LDS gather (+rare glb)
            src[k] = (int)e[k].y * W_ + (int)e[k].z; // y,x exact small ints
            f[k] = (src[k] < LDSPIX_)
                       ? lflow[src[k]]
                       : make_float2(fxp[src[k]], fyp[src[k]]);
        }
#pragma unroll
        for (int k = 0; k < 4; ++k) {
            int kk = q * 4 + k;
            val[kk] = false;
            if (idx[k] < N) {
                // Bit-exact numpy order: y + ((1 - ts) * f) * 160, no FMA.
                float dt = __fsub_rn(1.0f, e[k].x);
                float wy = __fadd_rn(e[k].y,
                                     __fmul_rn(__fmul_rn(dt, f[k].y), 160.0f));
                float wx = __fadd_rn(e[k].z,
                                     __fmul_rn(__fmul_rn(dt, f[k].x), 160.0f));
                float ry = rintf(wy);                // round half to even
                float rx = rintf(wx);
                // Validity on rounded floats (-0.0 valid, like the ref).
                if (ry >= 0.0f && ry < (float)H_ &&
                    rx >= 0.0f && rx < (float)W_) {
                    int iy = (int)ry, ix = (int)rx;
                    unsigned c = (e[k].w > 0.0f) ? 0u : 1u;
                    unsigned t = (unsigned)(iy * 2 + (ix >= 80));
                    pay[kk] = (unsigned)src[k] | (c << 15)
                            | ((unsigned)ix << 16);
                    tt[kk] = (unsigned short)t;
                    val[kk] = true;
                    rank[kk] = atomicAdd(&cnt[t], 1u);   // LDS rank
                }
            }
        }
    }
    __syncthreads();

    if (threadIdx.x < TILES_) {
        unsigned c = cnt[threadIdx.x];
        base[threadIdx.x] = c ? atomicAdd(&tails[b * TILES_ + threadIdx.x], c)
                              : 0u;
    }
    __syncthreads();

#pragma unroll
    for (int kk = 0; kk < 16; ++kk) {
        if (val[kk]) {
            unsigned pos = base[tt[kk]] + rank[kk];
            if (pos < SEG_CAP_)                      // ~never taken
                segs[((size_t)(b * TILES_ + tt[kk])) * SEG_CAP_ + pos]
                    = pay[kk];
        }
    }
}

// ---------------------------------------------------------------------------
// Pass B: one block per (b, dst tile). Exact dedup hash set on the payload
// key + count/contrib accumulators, all in LDS; fused divide + plain store.
// Termination: <= SEG_CAP_ = HASH_ events => empty slot always reachable.
// ---------------------------------------------------------------------------
__global__ __launch_bounds__(512) void accum_pass(
    const unsigned* __restrict__ tails,
    const unsigned* __restrict__ segs,
    float* __restrict__ out)                          // (B, 2, H, W)
{
    __shared__ unsigned hset[HASH_];                  // 32 KB
    __shared__ unsigned cntl[2 * 80];
    __shared__ unsigned cbl[2 * 80];

    const int bt = blockIdx.x;                        // b*TILES_ + t
    const int b = bt >> 8, t = bt & 255;
    const int row = t >> 1, half = t & 1;

    for (int j = threadIdx.x; j < HASH_; j += 512) hset[j] = EMPTY_;
    if (threadIdx.x < 160) { cntl[threadIdx.x] = 0u; cbl[threadIdx.x] = 0u; }
    __syncthreads();

    const unsigned n = min(tails[bt], (unsigned)SEG_CAP_);
    const unsigned* seg = segs + (size_t)bt * SEG_CAP_;
    volatile unsigned* hv = hset;

    for (unsigned i = threadIdx.x; i < n; i += 512) {
        unsigned key = seg[i];                        // src | pol<<15 | x<<16
        unsigned c = (key >> 15) & 1u;
        unsigned x = (key >> 16) & 0xFFu;
        unsigned cl = c * 80 + (x - (unsigned)half * 80u);

        unsigned h = mix32(key) & (HASH_ - 1);
        for (;;) {
            unsigned cur = hv[h];                     // cheap pre-read
            if (cur == key) break;                    // duplicate triple
            if (cur == EMPTY_) {
                unsigned prev = atomicCAS(&hset[h], EMPTY_, key);
                if (prev == EMPTY_) {                 // first (pol,src,fw)
                    atomicAdd(&cbl[cl], 1u);
                    break;
                }
                if (prev == key) break;               // raced duplicate
            }
            h = (h + 1) & (HASH_ - 1);
        }
        atomicAdd(&cntl[cl], 1u);                     // event count
    }
    __syncthreads();

    if (threadIdx.x < 160) {
        unsigned c = threadIdx.x / 80;
        unsigned xl = threadIdx.x % 80;
        unsigned cnt = cntl[threadIdx.x], cb = cbl[threadIdx.x];
        float r = (float)cnt;                         // cnt < 2^24: exact
        if (cb > 0u) r = __fdiv_rn(r, (float)cb);
        out[((size_t)(b * 2 + c)) * HW_ + row * W_ + half * 80 + xl] = r;
    }
}

extern "C" void kernel_launch(void* const* d_in, const int* in_sizes, int n_in,
                              void* d_out, int out_size, void* d_ws, size_t ws_size,
                              hipStream_t stream) {
    const float*  flow = (const float*)d_in[0];
    const float4* ev   = (const float4*)d_in[1];
    // d_in[2] (pol_mask) is redundant with event_list's p column — not read.

    int B = in_sizes[0] / (2 * HW_);          // = 4
    int N = in_sizes[1] / (B * 4);            // = 1,000,000

    // Workspace: [tails u32 x B*TILES_][segs u32 x B*TILES_*SEG_CAP_]
    unsigned* tails = (unsigned*)d_ws;
    unsigned* segs  = tails + (size_t)B * TILES_;

    hipMemsetAsync(tails, 0, (size_t)B * TILES_ * sizeof(unsigned), stream);

    dim3 gridA((N + EVB_ - 1) / EVB_, B);
    bin_pass<<<gridA, 1024, LDSPIX_ * sizeof(float2), stream>>>(
        ev, flow, tails, segs, N);

    accum_pass<<<B * TILES_, 512, 0, stream>>>(tails, segs, (float*)d_out);
}

// Round 12
// 140.402 us; speedup vs baseline: 1.1056x; 1.0057x over previous
//
#include <hip/hip_runtime.h>

#define H_ 128
#define W_ 160
#define HW_ (H_ * W_)
#define TILES_ 256        // dst tiles per batch: (row, x-half) = 128 x 2
#define SEG_CAP_ 8192     // events per tile seg: ~2.5x mean (~3300)
#define EVB_ 16384        // events per bin_pass block (1024 thr x 16)
#define LDSPIX_ 20096     // flow pixels cached in LDS (157 KB); the last
                          // 384 pixels (1.9% of events) gather from global.
#define HASH_ 8192        // LDS hash entries; >= SEG_CAP_ guarantees termination
#define EMPTY_ 0xFFFFFFFFu

__device__ __forceinline__ unsigned mix32(unsigned h) {
    h ^= h >> 16; h *= 0x85ebca6bu;
    h ^= h >> 13; h *= 0xc2b2ae35u;
    h ^= h >> 16;
    return h;
}

// ---------------------------------------------------------------------------
// Pass A: warp math per event, bin payloads by dst tile. Per-batch flow table
// in LDS (157 KB, 1 block/CU, 16 waves). r12 change: 8 stream loads in
// flight per thread (was 4) — the only untested lever for the ~40 us
// latency-exposure invariant.
// ---------------------------------------------------------------------------
__global__ __launch_bounds__(1024) void bin_pass(
    const float4* __restrict__ ev,       // (B, N, 4): ts, y, x, p
    const float* __restrict__ flow,      // (B, 2, HW) planar: ch0=fx, ch1=fy
    unsigned* __restrict__ tails,        // (B*TILES_), pre-zeroed
    unsigned* __restrict__ segs,         // (B*TILES_, SEG_CAP_)
    int N)
{
    extern __shared__ float2 lflow[];    // LDSPIX_ entries (dynamic, 157 KB)
    __shared__ unsigned cnt[TILES_];
    __shared__ unsigned base[TILES_];

    const int b = blockIdx.y;
    const int i0 = blockIdx.x * EVB_;
    const float4* evb = ev + (size_t)b * N;
    const float* fxp = flow + (size_t)b * 2 * HW_;   // fx plane
    const float* fyp = fxp + HW_;                    // fy plane

    // Fill LDS flow cache (coalesced planar reads) + zero tile counters.
    for (int j = threadIdx.x; j < LDSPIX_; j += 1024)
        lflow[j] = make_float2(fxp[j], fyp[j]);
    if (threadIdx.x < TILES_) cnt[threadIdx.x] = 0u;
    __syncthreads();

    unsigned pay[16], rank[16];
    unsigned short tt[16];
    bool val[16];

#pragma unroll
    for (int q = 0; q < 2; ++q) {                    // 2 sub-batches of 8
        float4 e[8];
        int idx[8];
#pragma unroll
        for (int k = 0; k < 8; ++k) {                // 8 stream loads in flight
            idx[k] = i0 + (q * 8 + k) * 1024 + (int)threadIdx.x;
            e[k] = (idx[k] < N) ? evb[idx[k]]
                                : make_float4(0.f, 0.f, 0.f, 0.f);
        }
        float2 f[8];
        int src[8];
#pragma unroll
        for (int k = 0; k < 8; ++k) {                // LDS gather (+rare glb)
            src[k] = (int)e[k].y * W_ + (int)e[k].z; // y,x exact small ints
            f[k] = (src[k] < LDSPIX_)
                       ? lflow[src[k]]
                       : make_float2(fxp[src[k]], fyp[src[k]]);
        }
#pragma unroll
        for (int k = 0; k < 8; ++k) {
            int kk = q * 8 + k;
            val[kk] = false;
            if (idx[k] < N) {
                // Bit-exact numpy order: y + ((1 - ts) * f) * 160, no FMA.
                float dt = __fsub_rn(1.0f, e[k].x);
                float wy = __fadd_rn(e[k].y,
                                     __fmul_rn(__fmul_rn(dt, f[k].y), 160.0f));
                float wx = __fadd_rn(e[k].z,
                                     __fmul_rn(__fmul_rn(dt, f[k].x), 160.0f));
                float ry = rintf(wy);                // round half to even
                float rx = rintf(wx);
                // Validity on rounded floats (-0.0 valid, like the ref).
                if (ry >= 0.0f && ry < (float)H_ &&
                    rx >= 0.0f && rx < (float)W_) {
                    int iy = (int)ry, ix = (int)rx;
                    unsigned c = (e[k].w > 0.0f) ? 0u : 1u;
                    unsigned t = (unsigned)(iy * 2 + (ix >= 80));
                    pay[kk] = (unsigned)src[k] | (c << 15)
                            | ((unsigned)ix << 16);
                    tt[kk] = (unsigned short)t;
                    val[kk] = true;
                    rank[kk] = atomicAdd(&cnt[t], 1u);   // LDS rank
                }
            }
        }
    }
    __syncthreads();

    if (threadIdx.x < TILES_) {
        unsigned c = cnt[threadIdx.x];
        base[threadIdx.x] = c ? atomicAdd(&tails[b * TILES_ + threadIdx.x], c)
                              : 0u;
    }
    __syncthreads();

#pragma unroll
    for (int kk = 0; kk < 16; ++kk) {
        if (val[kk]) {
            unsigned pos = base[tt[kk]] + rank[kk];
            if (pos < SEG_CAP_)                      // ~never taken
                segs[((size_t)(b * TILES_ + tt[kk])) * SEG_CAP_ + pos]
                    = pay[kk];
        }
    }
}

// ---------------------------------------------------------------------------
// Pass B: one block per (b, dst tile). Exact dedup hash set on the payload
// key + count/contrib accumulators, all in LDS; fused divide + plain store.
// Termination: <= SEG_CAP_ = HASH_ events => empty slot always reachable.
// ---------------------------------------------------------------------------
__global__ __launch_bounds__(512) void accum_pass(
    const unsigned* __restrict__ tails,
    const unsigned* __restrict__ segs,
    float* __restrict__ out)                          // (B, 2, H, W)
{
    __shared__ unsigned hset[HASH_];                  // 32 KB
    __shared__ unsigned cntl[2 * 80];
    __shared__ unsigned cbl[2 * 80];

    const int bt = blockIdx.x;                        // b*TILES_ + t
    const int b = bt >> 8, t = bt & 255;
    const int row = t >> 1, half = t & 1;

    for (int j = threadIdx.x; j < HASH_; j += 512) hset[j] = EMPTY_;
    if (threadIdx.x < 160) { cntl[threadIdx.x] = 0u; cbl[threadIdx.x] = 0u; }
    __syncthreads();

    const unsigned n = min(tails[bt], (unsigned)SEG_CAP_);
    const unsigned* seg = segs + (size_t)bt * SEG_CAP_;
    volatile unsigned* hv = hset;

    for (unsigned i = threadIdx.x; i < n; i += 512) {
        unsigned key = seg[i];                        // src | pol<<15 | x<<16
        unsigned c = (key >> 15) & 1u;
        unsigned x = (key >> 16) & 0xFFu;
        unsigned cl = c * 80 + (x - (unsigned)half * 80u);

        unsigned h = mix32(key) & (HASH_ - 1);
        for (;;) {
            unsigned cur = hv[h];                     // cheap pre-read
            if (cur == key) break;                    // duplicate triple
            if (cur == EMPTY_) {
                unsigned prev = atomicCAS(&hset[h], EMPTY_, key);
                if (prev == EMPTY_) {                 // first (pol,src,fw)
                    atomicAdd(&cbl[cl], 1u);
                    break;
                }
                if (prev == key) break;               // raced duplicate
            }
            h = (h + 1) & (HASH_ - 1);
        }
        atomicAdd(&cntl[cl], 1u);                     // event count
    }
    __syncthreads();

    if (threadIdx.x < 160) {
        unsigned c = threadIdx.x / 80;
        unsigned xl = threadIdx.x % 80;
        unsigned cnt = cntl[threadIdx.x], cb = cbl[threadIdx.x];
        float r = (float)cnt;                         // cnt < 2^24: exact
        if (cb > 0u) r = __fdiv_rn(r, (float)cb);
        out[((size_t)(b * 2 + c)) * HW_ + row * W_ + half * 80 + xl] = r;
    }
}

extern "C" void kernel_launch(void* const* d_in, const int* in_sizes, int n_in,
                              void* d_out, int out_size, void* d_ws, size_t ws_size,
                              hipStream_t stream) {
    const float*  flow = (const float*)d_in[0];
    const float4* ev   = (const float4*)d_in[1];
    // d_in[2] (pol_mask) is redundant with event_list's p column — not read.

    int B = in_sizes[0] / (2 * HW_);          // = 4
    int N = in_sizes[1] / (B * 4);            // = 1,000,000

    // Workspace: [tails u32 x B*TILES_][segs u32 x B*TILES_*SEG_CAP_]
    unsigned* tails = (unsigned*)d_ws;
    unsigned* segs  = tails + (size_t)B * TILES_;

    hipMemsetAsync(tails, 0, (size_t)B * TILES_ * sizeof(unsigned), stream);

    dim3 gridA((N + EVB_ - 1) / EVB_, B);
    bin_pass<<<gridA, 1024, LDSPIX_ * sizeof(float2), stream>>>(
        ev, flow, tails, segs, N);

    accum_pass<<<B * TILES_, 512, 0, stream>>>(tails, segs, (float*)d_out);
}